// Round 1
// baseline (392.346 us; speedup 1.0000x reference)
//
#include <hip/hip_runtime.h>
#include <hip/hip_bf16.h>

#define NODES 50000
#define EDGES 800000
#define CH 128
#define NCOL 512           // packed output cols: [ym1 | ym2 | yv1 | yv2]
#define MPAD 50048         // 391 * 128

typedef __attribute__((ext_vector_type(8))) __bf16 bf16x8;
typedef __attribute__((ext_vector_type(4))) float f32x4;

static __device__ __forceinline__ unsigned short f2bf(float f) {
    union { float f; unsigned u; } v; v.f = f;
    unsigned r = v.u + 0x7FFFu + ((v.u >> 16) & 1u);   // RNE
    return (unsigned short)(r >> 16);
}
static __device__ __forceinline__ float bf2f(unsigned short h) {
    union { unsigned u; float f; } v; v.u = ((unsigned)h) << 16;
    return v.f;
}

// ---- phase 0a: x fp32 -> bf16, padded to MPAD rows (pad rows = 0) ----
__global__ void k_cvt_x(const float* __restrict__ x, unsigned short* __restrict__ xb) {
    int i = blockIdx.x * blockDim.x + threadIdx.x;      // one group of 4 elems
    if (i >= MPAD * CH / 4) return;
    int base = i << 2;
    unsigned short s0 = 0, s1 = 0, s2 = 0, s3 = 0;
    if (base < NODES * CH) {                            // groups never straddle
        const f32x4 v = *reinterpret_cast<const f32x4*>(x + base);
        s0 = f2bf(v[0]); s1 = f2bf(v[1]); s2 = f2bf(v[2]); s3 = f2bf(v[3]);
    }
    unsigned long long p = (unsigned long long)s0 | ((unsigned long long)s1 << 16)
                         | ((unsigned long long)s2 << 32) | ((unsigned long long)s3 << 48);
    *reinterpret_cast<unsigned long long*>(xb + base) = p;
}

// ---- phase 0b: pack weights into Wb[512][128] bf16 (B^T layout) ----
__global__ void k_pack_w(const float* __restrict__ wm, const float* __restrict__ wv,
                         unsigned short* __restrict__ wb) {
    int i = blockIdx.x * blockDim.x + threadIdx.x;      // 0..65535
    if (i >= NCOL * CH) return;
    int n = i >> 7, k = i & 127;
    float v;
    if (n < 128)      v = wm[n * 256 + k];              // ym1: w_mean[:, :128]
    else if (n < 256) v = wm[(n - 128) * 256 + 128 + k];// ym2: w_mean[:, 128:]
    else if (n < 384) v = wv[(n - 256) * 256 + k];      // yv1
    else              v = wv[(n - 384) * 256 + 128 + k];// yv2
    wb[i] = f2bf(v);
}

// ---- phase 1: tables[MPAD][512] = Xb[MPAD][128] @ Wb[512][128]^T (MFMA bf16) ----
// LDS-free: K=128 total; A/B fragments loaded directly (B is 128KB, L2-resident).
template <bool TF32>
__global__ __launch_bounds__(256) void k_gemm(const unsigned short* __restrict__ xb,
                                              const unsigned short* __restrict__ wb,
                                              void* __restrict__ tab_) {
    float* tf = (float*)tab_;
    unsigned short* th = (unsigned short*)tab_;
    const int lane = threadIdx.x & 63;
    const int wave = threadIdx.x >> 6;
    const int rowbase = blockIdx.x * 128 + (wave >> 1) * 64;
    const int colbase = blockIdx.y * 128 + (wave & 1) * 64;
    const int lr = lane & 15;
    const int kg = lane >> 4;          // 0..3
    f32x4 acc[4][4] = {};
#pragma unroll
    for (int ks = 0; ks < 4; ++ks) {
        const int k = ks * 32 + kg * 8;
        bf16x8 af[4], bfr[4];
#pragma unroll
        for (int a = 0; a < 4; ++a)
            af[a] = *reinterpret_cast<const bf16x8*>(xb + (size_t)(rowbase + a * 16 + lr) * CH + k);
#pragma unroll
        for (int b = 0; b < 4; ++b)
            bfr[b] = *reinterpret_cast<const bf16x8*>(wb + (size_t)(colbase + b * 16 + lr) * CH + k);
#pragma unroll
        for (int a = 0; a < 4; ++a)
#pragma unroll
            for (int b = 0; b < 4; ++b)
                acc[a][b] = __builtin_amdgcn_mfma_f32_16x16x32_bf16(af[a], bfr[b], acc[a][b], 0, 0, 0);
    }
    // C/D layout: col = lane&15, row = (lane>>4)*4 + reg  [m89-verified]
    const int crow = (lane >> 4) * 4;
    const int ccol = lane & 15;
#pragma unroll
    for (int a = 0; a < 4; ++a)
#pragma unroll
        for (int b = 0; b < 4; ++b)
#pragma unroll
            for (int j = 0; j < 4; ++j) {
                int row = rowbase + a * 16 + crow + j;
                int col = colbase + b * 16 + ccol;
                size_t off = (size_t)row * NCOL + col;
                if (TF32) tf[off] = acc[a][b][j];
                else      th[off] = f2bf(acc[a][b][j]);
            }
}

// ---- phase 2: per-edge gather+add. One wave per edge.
// lanes 0..31: mean elems (float4 each); lanes 32..63: var elems.
template <bool TF32>
__global__ __launch_bounds__(256) void k_edges(const int* __restrict__ ei,
                                               const void* __restrict__ tab_,
                                               float* __restrict__ out) {
    const float* tf = (const float*)tab_;
    const unsigned short* th = (const unsigned short*)tab_;
    unsigned gt = blockIdx.x * (unsigned)blockDim.x + threadIdx.x;
    int gw = (int)(gt >> 6);                 // global wave id = edge id
    if (gw >= EDGES) return;
    const int lane = threadIdx.x & 63;
    const int half = lane >> 5;              // 0 = mean, 1 = var
    const int l = lane & 31;
    const int r = ei[gw];
    const int c = ei[EDGES + gw];
    size_t aoff = (size_t)r * NCOL + half * 256 + l * 4;        // ym1/yv1[row]
    size_t boff = (size_t)c * NCOL + 128 + half * 256 + l * 4;  // ym2/yv2[col]
    f32x4 av, bv;
    if (TF32) {
        av = *reinterpret_cast<const f32x4*>(tf + aoff);
        bv = *reinterpret_cast<const f32x4*>(tf + boff);
    } else {
        unsigned long long pa = *reinterpret_cast<const unsigned long long*>(th + aoff);
        unsigned long long pb = *reinterpret_cast<const unsigned long long*>(th + boff);
        av = f32x4{bf2f((unsigned short)pa), bf2f((unsigned short)(pa >> 16)),
                   bf2f((unsigned short)(pa >> 32)), bf2f((unsigned short)(pa >> 48))};
        bv = f32x4{bf2f((unsigned short)pb), bf2f((unsigned short)(pb >> 16)),
                   bf2f((unsigned short)(pb >> 32)), bf2f((unsigned short)(pb >> 48))};
    }
    f32x4 s = av + bv;
    size_t ooff = (size_t)half * ((size_t)EDGES * 128) + (size_t)gw * 128 + (size_t)l * 4;
    *reinterpret_cast<f32x4*>(out + ooff) = s;
}

// ---- last-resort fallback if ws is tiny: direct fp32 per-edge GEMV ----
__global__ void k_naive(const float* __restrict__ x, const int* __restrict__ ei,
                        const float* __restrict__ wm, const float* __restrict__ wv,
                        float* __restrict__ out) {
    __shared__ float xs[256];
    int e = blockIdx.x;
    int t = threadIdx.x;
    int r = ei[e], c = ei[EDGES + e];
    xs[t] = (t < 128) ? x[(size_t)r * 128 + t] : x[(size_t)c * 128 + (t - 128)];
    __syncthreads();
    const float* w = (t < 128) ? (wm + (size_t)t * 256) : (wv + (size_t)(t - 128) * 256);
    float acc = 0.f;
#pragma unroll 8
    for (int k = 0; k < 256; ++k) acc = fmaf(xs[k], w[k], acc);
    size_t ooff = (t < 128) ? ((size_t)e * 128 + t)
                            : ((size_t)EDGES * 128 + (size_t)e * 128 + (t - 128));
    out[ooff] = acc;
}

extern "C" void kernel_launch(void* const* d_in, const int* in_sizes, int n_in,
                              void* d_out, int out_size, void* d_ws, size_t ws_size,
                              hipStream_t stream) {
    const float* x  = (const float*)d_in[0];
    const int*   ei = (const int*)d_in[1];
    const float* wm = (const float*)d_in[2];
    const float* wv = (const float*)d_in[3];
    float* out = (float*)d_out;

    const size_t xb_b = (size_t)MPAD * CH * 2;     // 12,812,288 B
    const size_t wb_b = (size_t)NCOL * CH * 2;     //    131,072 B
    const size_t tf_b = (size_t)MPAD * NCOL * 4;   // 102,498,304 B (fp32 tables)
    const size_t th_b = (size_t)MPAD * NCOL * 2;   //  51,249,152 B (bf16 tables)

    unsigned short* xb = (unsigned short*)d_ws;
    unsigned short* wb = (unsigned short*)((char*)d_ws + xb_b);
    void* tab = (void*)((char*)d_ws + xb_b + wb_b);

    const bool f32tab = ws_size >= xb_b + wb_b + tf_b;
    const bool bftab  = !f32tab && ws_size >= xb_b + wb_b + th_b;

    if (!f32tab && !bftab) {           // correctness insurance only (slow)
        k_naive<<<EDGES, 256, 0, stream>>>(x, ei, wm, wv, out);
        return;
    }

    k_cvt_x<<<(MPAD * CH / 4 + 255) / 256, 256, 0, stream>>>(x, xb);
    k_pack_w<<<(NCOL * CH + 255) / 256, 256, 0, stream>>>(wm, wv, wb);
    dim3 g(MPAD / 128, NCOL / 128);
    unsigned eg = (unsigned)(((size_t)EDGES * 64 + 255) / 256);
    if (f32tab) {
        k_gemm<true><<<g, 256, 0, stream>>>(xb, wb, tab);
        k_edges<true><<<eg, 256, 0, stream>>>(ei, tab, out);
    } else {
        k_gemm<false><<<g, 256, 0, stream>>>(xb, wb, tab);
        k_edges<false><<<eg, 256, 0, stream>>>(ei, tab, out);
    }
}

// Round 2
// 272.187 us; speedup vs baseline: 1.4415x; 1.4415x over previous
//
#include <hip/hip_runtime.h>
#include <hip/hip_bf16.h>

#define NODES 50000
#define EDGES 800000
#define CH 128
#define NCOL 512           // packed cols per node: [ym1 | yv1 | ym2 | yv2]
#define MPAD 50048         // 391 * 128

typedef __attribute__((ext_vector_type(8))) __bf16 bf16x8;
typedef __attribute__((ext_vector_type(4))) float f32x4;

static __device__ __forceinline__ unsigned short f2bf(float f) {
    union { float f; unsigned u; } v; v.f = f;
    unsigned r = v.u + 0x7FFFu + ((v.u >> 16) & 1u);   // RNE
    return (unsigned short)(r >> 16);
}
static __device__ __forceinline__ float bf2f(unsigned short h) {
    union { unsigned u; float f; } v; v.u = ((unsigned)h) << 16;
    return v.f;
}

// ---- phase 0a: x fp32 -> bf16, padded to MPAD rows (pad rows = 0) ----
__global__ void k_cvt_x(const float* __restrict__ x, unsigned short* __restrict__ xb) {
    int i = blockIdx.x * blockDim.x + threadIdx.x;      // one group of 4 elems
    if (i >= MPAD * CH / 4) return;
    int base = i << 2;
    unsigned short s0 = 0, s1 = 0, s2 = 0, s3 = 0;
    if (base < NODES * CH) {                            // groups never straddle
        const f32x4 v = *reinterpret_cast<const f32x4*>(x + base);
        s0 = f2bf(v[0]); s1 = f2bf(v[1]); s2 = f2bf(v[2]); s3 = f2bf(v[3]);
    }
    unsigned long long p = (unsigned long long)s0 | ((unsigned long long)s1 << 16)
                         | ((unsigned long long)s2 << 32) | ((unsigned long long)s3 << 48);
    *reinterpret_cast<unsigned long long*>(xb + base) = p;
}

// ---- phase 0b: pack weights into Wb[512][128] bf16 (B^T layout) ----
// col n: [0,128) ym1 = w_mean[n][k]        [128,256) yv1 = w_var[n-128][k]
//        [256,384) ym2 = w_mean[n-256][128+k]  [384,512) yv2 = w_var[n-384][128+k]
__global__ void k_pack_w(const float* __restrict__ wm, const float* __restrict__ wv,
                         unsigned short* __restrict__ wb) {
    int i = blockIdx.x * blockDim.x + threadIdx.x;      // 0..65535
    if (i >= NCOL * CH) return;
    int n = i >> 7, k = i & 127;
    float v;
    if (n < 128)      v = wm[n * 256 + k];
    else if (n < 256) v = wv[(n - 128) * 256 + k];
    else if (n < 384) v = wm[(n - 256) * 256 + 128 + k];
    else              v = wv[(n - 384) * 256 + 128 + k];
    wb[i] = f2bf(v);
}

// ---- phase 1: tab[MPAD][512](bf16) = Xb[MPAD][128] @ Wb[512][128]^T (MFMA) ----
// LDS-free: K=128 total; B is 128 KB (L2-resident), A streamed once.
__global__ __launch_bounds__(256) void k_gemm(const unsigned short* __restrict__ xb,
                                              const unsigned short* __restrict__ wb,
                                              unsigned short* __restrict__ th) {
    const int lane = threadIdx.x & 63;
    const int wave = threadIdx.x >> 6;
    const int rowbase = blockIdx.x * 128 + (wave >> 1) * 64;
    const int colbase = blockIdx.y * 128 + (wave & 1) * 64;
    const int lr = lane & 15;
    const int kg = lane >> 4;          // 0..3
    f32x4 acc[4][4] = {};
#pragma unroll
    for (int ks = 0; ks < 4; ++ks) {
        const int k = ks * 32 + kg * 8;
        bf16x8 af[4], bfr[4];
#pragma unroll
        for (int a = 0; a < 4; ++a)
            af[a] = *reinterpret_cast<const bf16x8*>(xb + (size_t)(rowbase + a * 16 + lr) * CH + k);
#pragma unroll
        for (int b = 0; b < 4; ++b)
            bfr[b] = *reinterpret_cast<const bf16x8*>(wb + (size_t)(colbase + b * 16 + lr) * CH + k);
#pragma unroll
        for (int a = 0; a < 4; ++a)
#pragma unroll
            for (int b = 0; b < 4; ++b)
                acc[a][b] = __builtin_amdgcn_mfma_f32_16x16x32_bf16(af[a], bfr[b], acc[a][b], 0, 0, 0);
    }
    // C/D layout: col = lane&15, row = (lane>>4)*4 + reg  [m89-verified]
    const int crow = (lane >> 4) * 4;
    const int ccol = lane & 15;
#pragma unroll
    for (int a = 0; a < 4; ++a)
#pragma unroll
        for (int b = 0; b < 4; ++b)
#pragma unroll
            for (int j = 0; j < 4; ++j) {
                int row = rowbase + a * 16 + crow + j;
                int col = colbase + b * 16 + ccol;
                th[(size_t)row * NCOL + col] = f2bf(acc[a][b][j]);
            }
}

// ---- phase 2: per-edge gather+add. One wave per edge (grid exact).
// lanes 0..31: mean (ym1[r] + ym2[c]); lanes 32..63: var (yv1[r] + yv2[c]).
// Row-r data = bytes [0,512) of node row r (whole-wave contiguous); row-c = [512,1024).
__global__ __launch_bounds__(256) void k_edges(const int* __restrict__ ei,
                                               const unsigned short* __restrict__ th,
                                               float* __restrict__ out) {
    const int wave = threadIdx.x >> 6;                  // wave-uniform
    const int gw = blockIdx.x * 4 + wave;               // edge id, wave-uniform
    const int lane = threadIdx.x & 63;
    const int half = lane >> 5;                         // 0 = mean, 1 = var
    const int l = lane & 31;
    const int r = ei[gw];
    const int c = ei[EDGES + gw];
    const unsigned long long pa = *reinterpret_cast<const unsigned long long*>(
        th + (size_t)r * NCOL + half * 128 + l * 4);
    const unsigned long long pb = *reinterpret_cast<const unsigned long long*>(
        th + (size_t)c * NCOL + 256 + half * 128 + l * 4);
    f32x4 s;
    s[0] = bf2f((unsigned short)pa)         + bf2f((unsigned short)pb);
    s[1] = bf2f((unsigned short)(pa >> 16)) + bf2f((unsigned short)(pb >> 16));
    s[2] = bf2f((unsigned short)(pa >> 32)) + bf2f((unsigned short)(pb >> 32));
    s[3] = bf2f((unsigned short)(pa >> 48)) + bf2f((unsigned short)(pb >> 48));
    size_t ooff = (size_t)half * ((size_t)EDGES * 128) + (size_t)gw * 128 + (size_t)l * 4;
    __builtin_nontemporal_store(s, reinterpret_cast<f32x4*>(out + ooff));
}

// ---- last-resort fallback if ws is tiny: direct fp32 per-edge GEMV ----
__global__ void k_naive(const float* __restrict__ x, const int* __restrict__ ei,
                        const float* __restrict__ wm, const float* __restrict__ wv,
                        float* __restrict__ out) {
    __shared__ float xs[256];
    int e = blockIdx.x;
    int t = threadIdx.x;
    int r = ei[e], c = ei[EDGES + e];
    xs[t] = (t < 128) ? x[(size_t)r * 128 + t] : x[(size_t)c * 128 + (t - 128)];
    __syncthreads();
    const float* w = (t < 128) ? (wm + (size_t)t * 256) : (wv + (size_t)(t - 128) * 256);
    float acc = 0.f;
#pragma unroll 8
    for (int k = 0; k < 256; ++k) acc = fmaf(xs[k], w[k], acc);
    size_t ooff = (t < 128) ? ((size_t)e * 128 + t)
                            : ((size_t)EDGES * 128 + (size_t)e * 128 + (t - 128));
    out[ooff] = acc;
}

extern "C" void kernel_launch(void* const* d_in, const int* in_sizes, int n_in,
                              void* d_out, int out_size, void* d_ws, size_t ws_size,
                              hipStream_t stream) {
    const float* x  = (const float*)d_in[0];
    const int*   ei = (const int*)d_in[1];
    const float* wm = (const float*)d_in[2];
    const float* wv = (const float*)d_in[3];
    float* out = (float*)d_out;

    const size_t xb_b = (size_t)MPAD * CH * 2;     // 12,812,288 B
    const size_t wb_b = (size_t)NCOL * CH * 2;     //    131,072 B
    const size_t th_b = (size_t)MPAD * NCOL * 2;   //  51,249,152 B (bf16 tables)

    if (ws_size < xb_b + wb_b + th_b) {            // correctness insurance only
        k_naive<<<EDGES, 256, 0, stream>>>(x, ei, wm, wv, out);
        return;
    }

    unsigned short* xb  = (unsigned short*)d_ws;
    unsigned short* wb  = (unsigned short*)((char*)d_ws + xb_b);
    unsigned short* tab = (unsigned short*)((char*)d_ws + xb_b + wb_b);

    k_cvt_x<<<(MPAD * CH / 4 + 255) / 256, 256, 0, stream>>>(x, xb);
    k_pack_w<<<(NCOL * CH + 255) / 256, 256, 0, stream>>>(wm, wv, wb);
    dim3 g(MPAD / 128, NCOL / 128);
    k_gemm<<<g, 256, 0, stream>>>(xb, wb, tab);
    k_edges<<<EDGES / 4, 256, 0, stream>>>(ei, tab, out);
}